// Round 5
// baseline (435.074 us; speedup 1.0000x reference)
//
#include <hip/hip_runtime.h>
#include <math.h>

#define NPTS 8192
#define DCH  256
#define BB   32
#define TOTPT (BB * NPTS)            // 262144 points

// workspace layout (floats)
#define X1_OFF    0                          // 32*2*8192 = 524288
#define COS_OFF   (X1_OFF + BB * 2 * NPTS)   // 262144
#define SIN_OFF   (COS_OFF + TOTPT)          // 262144
#define X5_OFF    (SIN_OFF + TOTPT)          // 524288
#define STATS_OFF (X5_OFF + BB * 2 * NPTS)   // 128 floats

// ---------------------------------------------------------------------------
// block reduce (4 values) + atomic add to dst[0..3]  (dst = 16-way grouped)
// ---------------------------------------------------------------------------
__device__ __forceinline__ void block_reduce_atomic4(float v0, float v1,
                                                     float v2, float v3,
                                                     float* dst)
{
#pragma unroll
    for (int off = 32; off > 0; off >>= 1) {
        v0 += __shfl_down(v0, off, 64);
        v1 += __shfl_down(v1, off, 64);
        v2 += __shfl_down(v2, off, 64);
        v3 += __shfl_down(v3, off, 64);
    }
    __shared__ float red[4][4];
    const int wave = threadIdx.x >> 6, lane = threadIdx.x & 63;
    if (lane == 0) {
        red[wave][0] = v0; red[wave][1] = v1; red[wave][2] = v2; red[wave][3] = v3;
    }
    __syncthreads();
    if (threadIdx.x == 0) {
        float a0 = 0, a1 = 0, a2 = 0, a3 = 0;
#pragma unroll
        for (int w = 0; w < 4; ++w) {
            a0 += red[w][0]; a1 += red[w][1]; a2 += red[w][2]; a3 += red[w][3];
        }
        atomicAdd(dst + 0, a0); atomicAdd(dst + 1, a1);
        atomicAdd(dst + 2, a2); atomicAdd(dst + 3, a3);
    }
}

// per-output-channel conv update: taps (wa,wb,wc) against f0..f5
#define CONV_O(o, wa, wb, wc)                          \
    acc[o][0] += (wa) * f0 + (wb) * f1 + (wc) * f2;    \
    acc[o][1] += (wa) * f1 + (wb) * f2 + (wc) * f3;    \
    acc[o][2] += (wa) * f2 + (wb) * f3 + (wc) * f4;    \
    acc[o][3] += (wa) * f3 + (wb) * f4 + (wc) * f5;

// ---------------------------------------------------------------------------
// kernAB (v6): fused conv + offsets + pos-conv + rad. One block per (b,tile).
// R8 analysis: v5 hit ~124us vs the 38us BW floor. Harness fills run ALONE
// at 6.8 TB/s => true ceiling; v5's limiter was per-chunk exposed latency
// (1-deep prefetch slack ~600cyc < ~900-2000cyc HBM latency) with only 2
// independent blocks/CU (59KB LDS) to fill the stalls. v6: identical loop
// structure, chunks of 8 channels (fsh[2][8][264]=16.9KB) and Tsh OVERLAID
// on dead fsh => LDS ~37.6KB => 4 blocks/CU, 16 waves/CU. Cross-block TLP
// fills each block's barrier drains; in-flight ~32KB/CU > ~22KB needed.
// ---------------------------------------------------------------------------
__global__ __launch_bounds__(256) void kernAB(
    const float* __restrict__ pts, const float* __restrict__ feats,
    const float* __restrict__ rot_w, const float* __restrict__ rot_b,
    const float* __restrict__ trans_w, const float* __restrict__ trans_b,
    const float* __restrict__ pos_w, const float* __restrict__ pos_b,
    float* __restrict__ x1, float* __restrict__ cosA, float* __restrict__ sinA,
    float* __restrict__ stats)
{
    const int blk  = blockIdx.x;
    const int b    = blk >> 5;
    const int n0   = (blk & 31) << 8;
    const int tid  = threadIdx.x;
    const int wave = tid >> 6;
    const int lane = tid & 63;
    const int q    = lane << 2;          // 4 points per lane

    const float* fb = feats + (size_t)b * DCH * NPTS;

    // fsh[buf][r][j] = feats[chunk*8+r][n0-4+j]; main j=4..259, halo j=2,3,260,261
    // Overlaid by Tsh (1560 floats <= 4224) after the chunk loop.
    __shared__ __align__(16) float fsh[2][8][264];    // 16896 B
    __shared__ __align__(16) float wsh_mem[256 * 20]; // 20480 B; overlaid by red later
    __shared__ float hw4[4][12];

    float (*wsh)[20] = (float (*)[20])wsh_mem;

    // ---- phase 1b loads issued early (channel = tid); consumed after loop ----
    const float* fc = fb + (size_t)tid * NPTS;
    const int iA = (n0 >= 2) ? (n0 - 2) : 0;     // masked downstream if n0==0
    const int iB = (n0 >= 1) ? (n0 - 1) : 0;
    const float ha0 = fc[iA], ha1 = fc[iB], ha2 = fc[n0];
    const int jB = (n0 + 256 <= NPTS - 1) ? (n0 + 256) : (NPTS - 1);
    const int jC = (n0 + 257 <= NPTS - 1) ? (n0 + 257) : (NPTS - 1);
    const float hb0 = fc[n0 + 255], hb1 = fc[jB], hb2 = fc[jC];

    // ---- stage weights to LDS: wsh[c][o*3+k] ----
    for (int i = tid; i < 4608; i += 256) {
        float v; int o, r;
        if (i < 3072) { v = rot_w[i];          o = i / 768;              r = i % 768; }
        else          { v = trans_w[i - 3072]; o = 4 + (i - 3072) / 768; r = (i - 3072) % 768; }
        wsh[r / 3][o * 3 + (r % 3)] = v;
    }

    // ---- chunked double-buffered staging: 32 chunks x 8 channels ----
    // wave stages+computes its own 2 rows per chunk (rows 2w, 2w+1).
    const int r0w = wave << 1;

    float4 t0, t1; float2 hl;

#define STAGE_LOAD(c) {                                                        \
        const float* gp = fb + (size_t)(((c) << 3) + r0w) * NPTS + n0 + q;     \
        t0 = *(const float4*)(gp);                                             \
        t1 = *(const float4*)(gp + NPTS);                                      \
        hl = make_float2(0.0f, 0.0f);                                          \
        if (lane < 4) {                                                        \
            const size_t hb_ = (size_t)(((c) << 3) + r0w + (lane & 1)) * NPTS; \
            if ((lane >> 1) == 0) { if (n0 > 0)          hl = *(const float2*)(fb + hb_ + n0 - 2); } \
            else                  { if (n0 + 257 < NPTS) hl = *(const float2*)(fb + hb_ + n0 + 256); } \
        } }

#define STAGE_WRITE(c) {                                                       \
        const int bw_ = (c) & 1;                                               \
        *(float4*)&fsh[bw_][r0w + 0][4 + q] = t0;                              \
        *(float4*)&fsh[bw_][r0w + 1][4 + q] = t1;                              \
        if (lane < 4) *(float2*)&fsh[bw_][r0w + (lane & 1)][(lane >> 1) ? 260 : 2] = hl; }

    STAGE_LOAD(0)
    STAGE_WRITE(0)
    __syncthreads();   // wsh + chunk0 visible

    float acc[6][4];
#pragma unroll
    for (int o = 0; o < 6; ++o)
#pragma unroll
        for (int j = 0; j < 4; ++j) acc[o][j] = 0.0f;

#pragma unroll 1
    for (int c = 0; c < 32; ++c) {
        if (c < 31) STAGE_LOAD(c + 1)          // issue next-chunk loads first
        {
            const int bufr = c & 1;
#pragma unroll
            for (int rr = 0; rr < 2; ++rr) {
                const int ch = (c << 3) + r0w + rr;
                const float* wr = wsh[ch];                 // uniform -> broadcast
                const float4 wA = *(const float4*)(wr + 0);
                const float4 wB = *(const float4*)(wr + 4);
                const float4 wC = *(const float4*)(wr + 8);
                const float4 wD = *(const float4*)(wr + 12);
                const float2 wE = *(const float2*)(wr + 16);
                const float* dr = &fsh[bufr][r0w + rr][0];
                const float4 dA = *(const float4*)(dr + q);      // .w = f[n-1]
                const float4 dB = *(const float4*)(dr + q + 4);  // f[n..n+3]
                const float4 dC = *(const float4*)(dr + q + 8);  // .x = f[n+4]
                const float f0 = dA.w, f1 = dB.x, f2 = dB.y,
                            f3 = dB.z, f4 = dB.w, f5 = dC.x;
                CONV_O(0, wA.x, wA.y, wA.z)
                CONV_O(1, wA.w, wB.x, wB.y)
                CONV_O(2, wB.z, wB.w, wC.x)
                CONV_O(3, wC.y, wC.z, wC.w)
                CONV_O(4, wD.x, wD.y, wD.z)
                CONV_O(5, wD.w, wE.x, wE.y)
            }
        }
        if (c < 31) STAGE_WRITE(c + 1)         // vmcnt wait lands HERE, after compute
        __syncthreads();
    }

    // ---- phase 1b compute (wsh still intact; ha*/hb* loaded long ago) ----
    float hh[12];
    {
        const float* wrh = wsh[tid];
#pragma unroll
        for (int o = 0; o < 6; ++o) {
            const float w0 = wrh[o * 3], w1 = wrh[o * 3 + 1], w2 = wrh[o * 3 + 2];
            hh[o]     = w0 * ha0 + w1 * ha1 + w2 * ha2;   // left halo (n0-1)
            hh[6 + o] = w0 * hb0 + w1 * hb1 + w2 * hb2;   // right halo (n0+256)
        }
    }
#pragma unroll
    for (int off = 32; off > 0; off >>= 1)
#pragma unroll
        for (int j = 0; j < 12; ++j)
            hh[j] += __shfl_down(hh[j], off, 64);

    // wsh and fsh dead from here; overlay reduction scratch + Tsh
    __syncthreads();
    float (*red)[64][25] = (float (*)[64][25])wsh_mem;       // 4800 floats <= 5120
    float (*Tsh)[260]    = (float (*)[260])&fsh[0][0][0];    // 1560 floats <= 4224

    if (wave >= 1) {
#pragma unroll
        for (int o = 0; o < 6; ++o)
#pragma unroll
            for (int j = 0; j < 4; ++j)
                red[wave - 1][lane][o * 4 + j] = acc[o][j];
    }
    if (lane == 0) {
#pragma unroll
        for (int j = 0; j < 12; ++j) hw4[wave][j] = hh[j];
    }
    __syncthreads();

    if (wave == 0) {
#pragma unroll
        for (int w = 0; w < 3; ++w)
#pragma unroll
            for (int o = 0; o < 6; ++o)
#pragma unroll
                for (int j = 0; j < 4; ++j)
                    acc[o][j] += red[w][lane][o * 4 + j];
#pragma unroll
        for (int o = 0; o < 6; ++o) {
            const float bias = (o < 4) ? rot_b[o] : trans_b[o - 4];
#pragma unroll
            for (int j = 0; j < 4; ++j)
                Tsh[o][1 + (lane << 2) + j] = acc[o][j] + bias;
        }
    }
    if (tid < 12) {
        const int o = tid % 6, side = tid / 6;
        float v = hw4[0][tid] + hw4[1][tid] + hw4[2][tid] + hw4[3][tid];
        v += (o < 4) ? rot_b[o] : trans_b[o - 4];
        Tsh[o][side ? 257 : 0] = v;
    }
    __syncthreads();

    // ---------------- phase 2: offsets + pos-conv + rad ----------------
    const int n = n0 + tid;
    float tm[6][3];
#pragma unroll
    for (int o = 0; o < 6; ++o)
#pragma unroll
        for (int k = 0; k < 3; ++k)
            tm[o][k] = Tsh[o][tid + k];

    float xs0 = pos_b[0], xs1 = pos_b[1];
    float mz = -INFINITY;

#pragma unroll
    for (int m3 = 0; m3 < 3; ++m3) {
        const int m   = n + m3 - 1;
        const float msk = (m >= 0 && m < NPTS) ? 1.0f : 0.0f;
        const int mc  = (m < 0) ? 0 : ((m >= NPTS) ? NPTS - 1 : m);

        const float pa = pts[((size_t)b * 2 + 0) * NPTS + mc];
        const float pb = pts[((size_t)b * 2 + 1) * NPTS + mc];

        const float o0 = tm[0][m3] - 1.0f, o1 = tm[1][m3];
        const float o2 = tm[2][m3],        o3 = tm[3][m3] - 1.0f;
        const float tr0 = tm[4][m3],       tr1 = tm[5][m3];

        float p0 = pos_w[0 * 60 + 0 * 3 + m3] * pa + pos_w[0 * 60 + 1 * 3 + m3] * pb;
        float p1 = pos_w[1 * 60 + 0 * 3 + m3] * pa + pos_w[1 * 60 + 1 * 3 + m3] * pb;
#pragma unroll
        for (int k = 0; k < 9; ++k) {
            const float R0 = (float)(k / 3 - 1);
            const float R1 = (float)(k % 3 - 1);
            const float cx = o0 * R0 + o1 * R1 + tr0;
            const float cy = o2 * R0 + o3 * R1 + tr1;
            p0 += pos_w[0 * 60 + (2 + 2 * k) * 3 + m3] * cx
                + pos_w[0 * 60 + (3 + 2 * k) * 3 + m3] * cy;
            p1 += pos_w[1 * 60 + (2 + 2 * k) * 3 + m3] * cx
                + pos_w[1 * 60 + (3 + 2 * k) * 3 + m3] * cy;
            if (m3 == 1) {   // center tap: feed max-arctan (monotone => max z)
                const float z = (cy + 1e-6f) / (cx + 1e-6f);
                mz = fmaxf(mz, z);
            }
        }
        xs0 += msk * p0;
        xs1 += msk * p1;
    }

    const float mr = atanf(mz);
    float sv, cv;
    sincosf(mr, &sv, &cv);

    const int g = (b << 13) + n;
    x1[((size_t)b * 2 + 0) * NPTS + n] = xs0;
    x1[((size_t)b * 2 + 1) * NPTS + n] = xs1;
    cosA[g] = cv;
    sinA[g] = sv;

    block_reduce_atomic4(xs0, xs1, xs0 * xs0, xs1 * xs1,
                         stats + ((blk & 15) << 2));
}

// ---------------------------------------------------------------------------
// Kernel D: BN1 apply + leaky + rotate + ori-conv + BN2 stats. 1 thr/point.
// ---------------------------------------------------------------------------
__global__ __launch_bounds__(256) void kernD(
    const float* __restrict__ x1,
    const float* __restrict__ cosA, const float* __restrict__ sinA,
    const float* __restrict__ pos_g, const float* __restrict__ pos_beta,
    const float* __restrict__ ori_w, const float* __restrict__ ori_b,
    float* __restrict__ stats, float* __restrict__ x5)
{
    const int gg = blockIdx.x * 256 + threadIdx.x;
    const int b = gg >> 13;
    const int n = gg & (NPTS - 1);

    float s0 = 0, s1 = 0, s2 = 0, s3 = 0;
#pragma unroll
    for (int q = 0; q < 16; ++q) {
        s0 += stats[q * 4 + 0]; s1 += stats[q * 4 + 1];
        s2 += stats[q * 4 + 2]; s3 += stats[q * 4 + 3];
    }
    const float cntInv = 1.0f / (float)TOTPT;
    const float m0 = s0 * cntInv, m1 = s1 * cntInv;
    const float var0 = s2 * cntInv - m0 * m0;
    const float var1 = s3 * cntInv - m1 * m1;
    const float i0 = rsqrtf(var0 + 1e-5f), i1 = rsqrtf(var1 + 1e-5f);
    const float g0 = pos_g[0], g1 = pos_g[1];
    const float be0 = pos_beta[0], be1 = pos_beta[1];

    float x4a[3], x4b[3];
#pragma unroll
    for (int m3 = 0; m3 < 3; ++m3) {
        const int m   = n + m3 - 1;
        const float msk = (m >= 0 && m < NPTS) ? 1.0f : 0.0f;
        const int mc  = (m < 0) ? 0 : ((m >= NPTS) ? NPTS - 1 : m);
        float y0 = x1[((size_t)b * 2 + 0) * NPTS + mc];
        float y1 = x1[((size_t)b * 2 + 1) * NPTS + mc];
        y0 = g0 * (y0 - m0) * i0 + be0;
        y1 = g1 * (y1 - m1) * i1 + be1;
        y0 = (y0 >= 0.0f) ? y0 : 0.2f * y0;
        y1 = (y1 >= 0.0f) ? y1 : 0.2f * y1;
        const float cv = cosA[(b << 13) + mc];
        const float sv = sinA[(b << 13) + mc];
        x4a[m3] = (y0 * cv - y1 * sv) * msk;
        x4b[m3] = (y0 * sv + y1 * cv) * msk;
    }

    float z0 = ori_b[0], z1 = ori_b[1];
#pragma unroll
    for (int k = 0; k < 3; ++k) {
        z0 += ori_w[0 * 6 + 0 * 3 + k] * x4a[k] + ori_w[0 * 6 + 1 * 3 + k] * x4b[k];
        z1 += ori_w[1 * 6 + 0 * 3 + k] * x4a[k] + ori_w[1 * 6 + 1 * 3 + k] * x4b[k];
    }
    x5[((size_t)b * 2 + 0) * NPTS + n] = z0;
    x5[((size_t)b * 2 + 1) * NPTS + n] = z1;

    block_reduce_atomic4(z0, z1, z0 * z0, z1 * z1,
                         stats + 64 + ((blockIdx.x & 15) << 2));
}

// ---------------------------------------------------------------------------
// Kernel E: BN2 apply -> out
// ---------------------------------------------------------------------------
__global__ __launch_bounds__(256) void kernE(
    const float* __restrict__ x5, const float* __restrict__ stats,
    const float* __restrict__ ori_g, const float* __restrict__ ori_beta,
    float* __restrict__ out)
{
    const int gg = blockIdx.x * 256 + threadIdx.x;  // 0..524287
    const int o = (gg >> 13) & 1;
    float sm = 0, sq = 0;
#pragma unroll
    for (int q = 0; q < 16; ++q) {
        sm += stats[64 + q * 4 + o];
        sq += stats[64 + q * 4 + 2 + o];
    }
    const float cntInv = 1.0f / (float)TOTPT;
    const float m  = sm * cntInv;
    const float vv = sq * cntInv - m * m;
    const float inv = rsqrtf(vv + 1e-5f);
    out[gg] = ori_g[o] * (x5[gg] - m) * inv + ori_beta[o];
}

// ---------------------------------------------------------------------------
extern "C" void kernel_launch(void* const* d_in, const int* in_sizes, int n_in,
                              void* d_out, int out_size, void* d_ws, size_t ws_size,
                              hipStream_t stream)
{
    const float* pts      = (const float*)d_in[0];
    const float* feats    = (const float*)d_in[1];
    const float* rot_w    = (const float*)d_in[2];
    const float* rot_b    = (const float*)d_in[3];
    const float* trans_w  = (const float*)d_in[4];
    const float* trans_b  = (const float*)d_in[5];
    const float* pos_w    = (const float*)d_in[6];
    const float* pos_b    = (const float*)d_in[7];
    const float* pos_g    = (const float*)d_in[8];
    const float* pos_beta = (const float*)d_in[9];
    const float* ori_w    = (const float*)d_in[10];
    const float* ori_b    = (const float*)d_in[11];
    const float* ori_g    = (const float*)d_in[12];
    const float* ori_beta = (const float*)d_in[13];

    float* ws    = (float*)d_ws;
    float* x1    = ws + X1_OFF;
    float* cosA  = ws + COS_OFF;
    float* sinA  = ws + SIN_OFF;
    float* x5    = ws + X5_OFF;
    float* stats = ws + STATS_OFF;

    hipMemsetAsync(stats, 0, 128 * sizeof(float), stream);

    kernAB<<<1024, 256, 0, stream>>>(pts, feats, rot_w, rot_b, trans_w, trans_b,
                                     pos_w, pos_b, x1, cosA, sinA, stats);
    kernD<<<1024, 256, 0, stream>>>(x1, cosA, sinA, pos_g, pos_beta,
                                    ori_w, ori_b, stats, x5);
    kernE<<<2048, 256, 0, stream>>>(x5, stats, ori_g, ori_beta, (float*)d_out);
}